// Round 4
// baseline (1372.138 us; speedup 1.0000x reference)
//
#include <hip/hip_runtime.h>
#include <math.h>

typedef float vf4 __attribute__((ext_vector_type(4)));

#define CODE_SIZE 1024
#define CODE_DIM  256
#define BB        64
#define HWSZ      1024                       // H*W = 32*32
#define NROWS     (BB * HWSZ)                // 65536
#define QELEMS    (BB * CODE_DIM * HWSZ)     // 16777216

// ---------------------------------------------------------------------------
// sw[code] = numpy-pairwise sum of fl(w*w) over 256 contiguous elements.
// ---------------------------------------------------------------------------
__global__ void k_sumsq_w(const float* __restrict__ w, float* __restrict__ sw) {
#pragma clang fp contract(off)
  const int code = blockIdx.x * blockDim.x + threadIdx.x;
  if (code >= CODE_SIZE) return;
  const float* row = w + (size_t)code * CODE_DIM;
  float halves[2];
  for (int h = 0; h < 2; ++h) {
    const float* p = row + h * 128;
    float r[8];
#pragma unroll
    for (int j = 0; j < 8; ++j) { float v = p[j]; r[j] = v * v; }
    for (int i = 8; i < 128; i += 8) {
#pragma unroll
      for (int j = 0; j < 8; ++j) { float v = p[i + j]; r[j] += v * v; }
    }
    halves[h] = ((r[0] + r[1]) + (r[2] + r[3])) + ((r[4] + r[5]) + (r[6] + r[7]));
  }
  sw[code] = halves[0] + halves[1];
}

// sx[n] = same pairwise over fl(x*x), x strided by HWSZ along channel dim.
__global__ void k_sumsq_x(const float* __restrict__ x, float* __restrict__ sx) {
#pragma clang fp contract(off)
  const int n = blockIdx.x * blockDim.x + threadIdx.x;   // 0..65535
  const int b = n >> 10, hw = n & 1023;
  const float* p = x + (size_t)b * CODE_DIM * HWSZ + hw;
  float halves[2];
  for (int h = 0; h < 2; ++h) {
    const float* q = p + (size_t)(h * 128) * HWSZ;
    float r[8];
#pragma unroll
    for (int j = 0; j < 8; ++j) { float v = q[(size_t)j * HWSZ]; r[j] = v * v; }
    for (int i = 8; i < 128; i += 8) {
#pragma unroll
      for (int j = 0; j < 8; ++j) { float v = q[(size_t)(i + j) * HWSZ]; r[j] += v * v; }
    }
    halves[h] = ((r[0] + r[1]) + (r[2] + r[3])) + ((r[4] + r[5]) + (r[6] + r[7]));
  }
  sx[n] = halves[0] + halves[1];
}

// wT[k][code] = w[code][k]. Reads strided (L2 absorbs 1 MB), writes coalesced.
__global__ void k_transpose(const float* __restrict__ w, float* __restrict__ wT) {
  const int k = blockIdx.x;          // 0..255
  const int t = threadIdx.x;         // 0..255
#pragma unroll
  for (int i = 0; i < 4; ++i) {
    const int c = i * 256 + t;
    wT[(size_t)k * CODE_SIZE + c] = w[(size_t)c * CODE_DIM + k];
  }
}

// ---------------------------------------------------------------------------
// GEMM-argmin, LDS-pipe-minimal form. Block = 32 rows x 1024 codes
// (4 chunks of 256; lane <-> code). Per k: 1 conflict-free ds_read_b32 for w
// + 32 fmaf whose x operand is a block-uniform SGPR (s_load_dwordx16 path,
// SMEM pipe — off the LDS pipe). Round-3 was LDS-bound: 64 FMA per 4
// ds_read_b128 -> VALUBusy ceiling 64/96=67% (measured 66%). Here per-CU
// per k: VALU 256 cyc vs LDS ~140 cyc -> VALU-bound.
// Accumulator: single sequential fmaf chain over k=0..255 (chunk-outer,
// kc-inner) — bitwise-matching np's sgemm. Key = fl(fl(sx-2G)+sw), contract
// off. Tie-break lowest code everywhere (ascending scans + strict <, with
// explicit code compare on equal keys).
// LDS: ws 32 KB (overlaid by per-chunk reduction) + 2 KB -> 4 blocks/CU.
// ---------------------------------------------------------------------------
#define RT 32                       // rows per block
#define KC 32                       // k per staging step
#define NCHUNK 4

__launch_bounds__(256, 4)
__global__ void k_argmin(const float* __restrict__ x, const float* __restrict__ wT,
                         const float* __restrict__ sx, const float* __restrict__ sw,
                         float* __restrict__ oidx) {
  __shared__ float ws[KC * 256];        // [k][code-in-chunk], 32 KB
  __shared__ float r2k[256], r2i[256];  // stage-2 reduction scratch, 2 KB

  const int t   = threadIdx.x;
  const int n0  = blockIdx.x * RT;
  const int b   = n0 >> 10;
  const int hw0 = n0 & 1023;

  // running best per row, held by threads t<32 (row = t) after per-chunk
  // LDS reductions — keeps bk/bi out of the register budget.
  float rbk = INFINITY, rbi = (float)CODE_SIZE;

  for (int chunk = 0; chunk < NCHUNK; ++chunk) {
    const int code0 = chunk * 256;

    float acc[RT];
#pragma unroll
    for (int r = 0; r < RT; ++r) acc[r] = 0.0f;

    for (int kc = 0; kc < CODE_DIM / KC; ++kc) {
      const int kb = kc * KC;
      __syncthreads();   // protect ws from previous readers
      // stage ws[kk][0..255] = wT[kb+kk][code0..code0+255]; 2048 vf4 jobs,
      // per-wave fully coalesced 1 KB global reads + contiguous LDS writes.
#pragma unroll
      for (int i = 0; i < 8; ++i) {
        const int j  = t + 256 * i;
        const int kk = j >> 6;       // wave-uniform
        const int c4 = j & 63;
        vf4 v = *(const vf4*)(wT + (size_t)(kb + kk) * CODE_SIZE + code0 + c4 * 4);
        *(vf4*)(ws + kk * 256 + c4 * 4) = v;
      }
      __syncthreads();

      const float* xbase = x + (size_t)(b * CODE_DIM + kb) * HWSZ + hw0;
#pragma unroll 4
      for (int k = 0; k < KC; ++k) {
        const float wv = ws[k * 256 + t];            // ds_read_b32, bank=t%32
        const float* xr = xbase + (size_t)k * HWSZ;  // block-uniform -> s_load
#pragma unroll
        for (int r = 0; r < RT; ++r)
          acc[r] = fmaf(xr[r], wv, acc[r]);
      }
    }

    // keys for this chunk; then per-chunk cross-thread reduction via LDS
    // (overlaid on ws — contents are dead until next chunk's staging).
    float key[RT];
    {
#pragma clang fp contract(off)
      const int code = code0 + t;
      const float swv = sw[code];
#pragma unroll
      for (int r = 0; r < RT; ++r) {
        const float tmp = sx[n0 + r] - 2.0f * acc[r];  // fl(sx - 2G)
        key[r] = tmp + swv;                            // fl(.. + sw)
      }
    }
    const float codef = (float)(code0 + t);
#pragma unroll
    for (int h = 0; h < 2; ++h) {      // rows h*16 .. h*16+15
      float* redk = ws;                // [16][256]
      float* redi = ws + 16 * 256;
      __syncthreads();
#pragma unroll
      for (int j = 0; j < 16; ++j) {
        redk[j * 256 + t] = key[h * 16 + j];
        redi[j * 256 + t] = codef;
      }
      __syncthreads();
      {
        const int row = t >> 4, seg = t & 15;
        float k0 = INFINITY, i0 = (float)CODE_SIZE;
        for (int c = 0; c < 16; ++c) {           // ascending codes
          const float kq = redk[row * 256 + seg * 16 + c];
          const float iq = redi[row * 256 + seg * 16 + c];
          if (kq < k0 || (kq == k0 && iq < i0)) { k0 = kq; i0 = iq; }
        }
        r2k[t] = k0; r2i[t] = i0;
      }
      __syncthreads();
      if ((t >> 4) == h && (t & 15) < 16) {      // threads h*16..h*16+15? no:
      }
      if (t < 16) {
        const int row = h * 16 + t;
        float k0 = r2k[t * 16], i0 = r2i[t * 16];
        for (int s = 1; s < 16; ++s) {           // seg order arbitrary: we
          const float kq = r2k[t * 16 + s];      // compare real code ids
          const float iq = r2i[t * 16 + s];
          if (kq < k0 || (kq == k0 && iq < i0)) { k0 = kq; i0 = iq; }
        }
        // merge into running best for this row (held by thread `row`? —
        // we instead merge here and hand off via registers below)
        r2k[t] = k0; r2i[t] = i0;   // compact: slot t = row h*16+t
      }
      __syncthreads();
      if (t < RT) {
        const int hh = t >> 4;       // which half this row belongs to
        if (hh == h) {
          const float kq = r2k[t & 15], iq = r2i[t & 15];
          if (kq < rbk || (kq == rbk && iq < rbi)) { rbk = kq; rbi = iq; }
        }
      }
      __syncthreads();
    }
  }

  if (t < RT) oidx[n0 + t] = rbi;   // idx output read back as fp32

}

// ---------------------------------------------------------------------------
// Epilogue: block = (b, 64-hw tile). Stage the 64 gathered w-rows into LDS,
// then fully-coalesced vf4 global reads/writes for q and ste = fl(fl(q-x)+x).
// ---------------------------------------------------------------------------
#define MT 64
#define WT_S 65

__global__ void k_epilogue(const float* __restrict__ x, const float* __restrict__ w,
                           const float* __restrict__ oidx, float* __restrict__ out) {
#pragma clang fp contract(off)
  __shared__ int   idxs[MT];
  __shared__ float wt[CODE_DIM * WT_S];   // wt[c][r], 66560 B

  const int t   = threadIdx.x;
  const int n0  = blockIdx.x * MT;
  const int b   = n0 >> 10;
  const int hw0 = n0 & 1023;

  if (t < MT) idxs[t] = (int)oidx[n0 + t];
  __syncthreads();

#pragma unroll
  for (int i = 0; i < 16; ++i) {
    const int j  = t + 256 * i;
    const int r  = j & 63;
    const int cq = j >> 6;     // 0..63
    vf4 v = *(const vf4*)(w + (size_t)idxs[r] * CODE_DIM + cq * 4);
    wt[(cq * 4 + 0) * WT_S + r] = v.x;
    wt[(cq * 4 + 1) * WT_S + r] = v.y;
    wt[(cq * 4 + 2) * WT_S + r] = v.z;
    wt[(cq * 4 + 3) * WT_S + r] = v.w;
  }
  __syncthreads();

#pragma unroll
  for (int i = 0; i < 16; ++i) {
    const int j  = t + 256 * i;
    const int c  = j >> 4;     // 0..255
    const int rq = j & 15;
    const size_t off = (size_t)(b * CODE_DIM + c) * HWSZ + hw0 + rq * 4;
    vf4 xv = *(const vf4*)(x + off);
    vf4 q, s;
#pragma unroll
    for (int u = 0; u < 4; ++u) {
      const float qv = wt[c * WT_S + rq * 4 + u];
      q[u] = qv;
      const float d = qv - xv[u];
      s[u] = d + xv[u];
    }
    *(vf4*)(out + off) = q;
    *(vf4*)(out + (size_t)QELEMS + off) = s;
  }
}

extern "C" void kernel_launch(void* const* d_in, const int* in_sizes, int n_in,
                              void* d_out, int out_size, void* d_ws, size_t ws_size,
                              hipStream_t stream) {
  const float* x = (const float*)d_in[0];   // (64,256,32,32) fp32
  const float* w = (const float*)d_in[1];   // (1024,256) fp32
  float* out  = (float*)d_out;
  float* oidx = out + 2 * (size_t)QELEMS;          // idx region (written as float)
  // scratch (sx, sw, wT) lives inside the ste output region; the epilogue —
  // which runs last, stream-ordered — overwrites the whole region.
  float* sx = out + (size_t)QELEMS;                // 65536 floats
  float* sw = out + (size_t)QELEMS + NROWS;        // 1024 floats
  float* wT = out + (size_t)QELEMS + 131072;       // 256x1024 floats (1 MB)

  k_transpose<<<CODE_DIM, 256, 0, stream>>>(w, wT);
  k_sumsq_w<<<CODE_SIZE / 256, 256, 0, stream>>>(w, sw);
  k_sumsq_x<<<NROWS / 256, 256, 0, stream>>>(x, sx);
  k_argmin<<<NROWS / RT, 256, 0, stream>>>(x, wT, sx, sw, oidx);
  k_epilogue<<<NROWS / MT, 256, 0, stream>>>(x, w, oidx, out);
}